// Round 1
// 280.525 us; speedup vs baseline: 1.0173x; 1.0173x over previous
//
#include <hip/hip_runtime.h>

#define F1 128
#define F2 64
// bucket = 512 consecutive nodes; requires N <= 256*512 and N < 2^17 (u32 ebuf pack)
#define BSH 9
#define BSZ 512

typedef unsigned int u32;
typedef unsigned short u16;
typedef __attribute__((ext_vector_type(8))) short bf16x8;   // 8 bf16 (4 VGPRs)
typedef __attribute__((ext_vector_type(4))) float f32x4;

// bf16 helpers (manual, header-version-proof). RNE pack, shift unpack.
__device__ __forceinline__ u32 bf16rne(float f) {
    u32 u = __float_as_uint(f);
    return (u + 0x7FFFu + ((u >> 16) & 1u)) >> 16;
}
__device__ __forceinline__ u32 pack2(float lo, float hi) {
    return bf16rne(lo) | (bf16rne(hi) << 16);
}
__device__ __forceinline__ float bflo(u32 u) { return __uint_as_float(u << 16); }
__device__ __forceinline__ float bfhi(u32 u) { return __uint_as_float(u & 0xFFFF0000u); }

__device__ __forceinline__ void acc8(float* ax, uint4 v) {
    ax[0] += bflo(v.x); ax[1] += bfhi(v.x);
    ax[2] += bflo(v.y); ax[3] += bfhi(v.y);
    ax[4] += bflo(v.z); ax[5] += bfhi(v.z);
    ax[6] += bflo(v.w); ax[7] += bfhi(v.w);
}

// ---------------- CSR build (bucketed, LDS atomics) ----------------

__global__ __launch_bounds__(256) void k_bhist(const int* __restrict__ colv,
                                               int* __restrict__ bucket_cnt, int E) {
    __shared__ int l[256];
    int t = threadIdx.x;
    l[t] = 0;
    __syncthreads();
    for (int e = blockIdx.x * blockDim.x + t; e < E; e += gridDim.x * blockDim.x)
        atomicAdd(&l[colv[e] >> BSH], 1);
    __syncthreads();
    if (l[t]) atomicAdd(&bucket_cnt[t], l[t]);
}

__global__ __launch_bounds__(256) void k_bscan(const int* __restrict__ bucket_cnt,
                                               int* __restrict__ bucket_base,
                                               int* __restrict__ bucket_cur,
                                               int* __restrict__ rowptr_last,
                                               int NB, int E) {
    __shared__ int s[256];
    int t = threadIdx.x;
    int v = (t < NB) ? bucket_cnt[t] : 0;
    s[t] = v;
    __syncthreads();
    for (int d = 1; d < 256; d <<= 1) {
        int u = (t >= d) ? s[t - d] : 0;
        __syncthreads();
        s[t] += u;
        __syncthreads();
    }
    int excl = s[t] - v;
    if (t < NB) { bucket_base[t] = excl; bucket_cur[t] = excl; }
    if (t == NB - 1) bucket_base[NB] = s[t];
    if (t == 0) *rowptr_last = E;
}

// Stage 4096 edges in registers, reserve per-bucket runs with ONE global atomic
// per bucket, write packed (c_local<<17 | row) u32 bucket-major.
__global__ __launch_bounds__(256) void k_part(const int* __restrict__ rowv,
                                              const int* __restrict__ colv,
                                              int* __restrict__ bucket_cur,
                                              u32* __restrict__ ebuf, int E) {
    __shared__ int lcnt[256], lbase[256], loff[256];
    int t = threadIdx.x;
    lcnt[t] = 0; loff[t] = 0;
    __syncthreads();
    int rows[16], cols[16];
    int e0 = blockIdx.x * 4096;
#pragma unroll
    for (int it = 0; it < 16; it++) {
        int e = e0 + it * 256 + t;
        bool v = e < E;
        cols[it] = v ? colv[e] : -1;
        rows[it] = v ? rowv[e] : 0;
        if (v) atomicAdd(&lcnt[cols[it] >> BSH], 1);
    }
    __syncthreads();
    if (lcnt[t]) lbase[t] = atomicAdd(&bucket_cur[t], lcnt[t]);
    __syncthreads();
#pragma unroll
    for (int it = 0; it < 16; it++) {
        if (cols[it] >= 0) {
            int b = cols[it] >> BSH;
            int p = lbase[b] + atomicAdd(&loff[b], 1);
            ebuf[p] = ((u32)(cols[it] & (BSZ - 1)) << 17) | (u32)rows[it];
        }
    }
}

// One block per bucket: per-node counts + scan + placement all via LDS.
__global__ __launch_bounds__(512) void k_bfill(const u32* __restrict__ ebuf,
                                               const int* __restrict__ bucket_base,
                                               int* __restrict__ rowptr,
                                               float* __restrict__ dis,
                                               int* __restrict__ adj, int N) {
    __shared__ int cnt[BSZ], scn[BSZ], cur[BSZ];
    int t = threadIdx.x;
    int b = blockIdx.x;
    int e0 = bucket_base[b], e1 = bucket_base[b + 1];
    cnt[t] = 0;
    __syncthreads();
    for (int i = e0 + t; i < e1; i += BSZ)
        atomicAdd(&cnt[ebuf[i] >> 17], 1);
    __syncthreads();
    scn[t] = cnt[t];
    __syncthreads();
    for (int d = 1; d < BSZ; d <<= 1) {
        int u = (t >= d) ? scn[t - d] : 0;
        __syncthreads();
        scn[t] += u;
        __syncthreads();
    }
    int excl = scn[t] - cnt[t];
    cur[t] = excl;
    int node = (b << BSH) + t;
    if (node < N) {
        rowptr[node] = e0 + excl;
        dis[node] = rsqrtf((float)(cnt[t] + 1));   // +1 self loop
    }
    __syncthreads();
    for (int i = e0 + t; i < e1; i += BSZ) {
        u32 p = ebuf[i];
        int c = p >> 17;
        int r = (int)(p & 0x1FFFFu);
        int pos = atomicAdd(&cur[c], 1);
        adj[e0 + pos] = r;
    }
}

// ---------------- W prep: fp32 W[K][C] -> bf16 B-frag order [kb][nb][lane][j] ----------------
// Frag layout for mfma_f32_16x16x32_bf16 B-operand: n = lane&15, k = (lane>>4)*8 + j.
// Blocks 0-7: W1 (NBc=8). Blocks 8-11: W2 (NBc=4).

__device__ __forceinline__ void wprep_do(const float* __restrict__ W,
                                         uint4* __restrict__ wf, int NBc, int t) {
    int lane = t & 63;
    int rem = t >> 6;
    int nb = rem % NBc;
    int kb = rem / NBc;
    int C = NBc * 16;
    int col = nb * 16 + (lane & 15);
    int krow = kb * 32 + (lane >> 4) * 8;
    u32 w[4];
#pragma unroll
    for (int p = 0; p < 4; p++) {
        float lo = W[(size_t)(krow + 2 * p) * C + col];
        float hi = W[(size_t)(krow + 2 * p + 1) * C + col];
        w[p] = pack2(lo, hi);
    }
    wf[t] = make_uint4(w[0], w[1], w[2], w[3]);
}

__global__ __launch_bounds__(256) void k_wprep(const float* __restrict__ W1,
                                               const float* __restrict__ W2,
                                               uint4* __restrict__ w1f,
                                               uint4* __restrict__ w2f) {
    int blk = blockIdx.x;
    if (blk < 8) wprep_do(W1, w1f, 8, blk * 256 + threadIdx.x);
    else         wprep_do(W2, w2f, 4, (blk - 8) * 256 + threadIdx.x);
}

// ---------------- GEMM 1 (MFMA): g1(bf16) = dis[row] * (x @ W1) ----------------

__global__ __launch_bounds__(256, 4) void k_gemm1(const float* __restrict__ x,
                                                  const uint4* __restrict__ w1f,
                                                  const float* __restrict__ dis,
                                                  u16* __restrict__ gb, int N) {
    int lane = threadIdx.x & 63;
    int wave = threadIdx.x >> 6;
    int m = lane & 15, quad = lane >> 4;
    int row0 = blockIdx.x * 64 + wave * 16;
    int arow = min(row0 + m, N - 1);
    const float* xr = x + (size_t)arow * F1 + quad * 8;
    bf16x8 a[4];
#pragma unroll
    for (int kb = 0; kb < 4; kb++) {
        float4 lo = *(const float4*)(xr + kb * 32);
        float4 hi = *(const float4*)(xr + kb * 32 + 4);
        a[kb][0] = (short)bf16rne(lo.x); a[kb][1] = (short)bf16rne(lo.y);
        a[kb][2] = (short)bf16rne(lo.z); a[kb][3] = (short)bf16rne(lo.w);
        a[kb][4] = (short)bf16rne(hi.x); a[kb][5] = (short)bf16rne(hi.y);
        a[kb][6] = (short)bf16rne(hi.z); a[kb][7] = (short)bf16rne(hi.w);
    }
    f32x4 acc[8];
#pragma unroll
    for (int nb = 0; nb < 8; nb++) acc[nb] = (f32x4)(0.0f);
#pragma unroll
    for (int nb = 0; nb < 8; nb++) {
#pragma unroll
        for (int kb = 0; kb < 4; kb++) {
            uint4 braw = w1f[(kb * 8 + nb) * 64 + lane];
            bf16x8 bf = *(bf16x8*)&braw;
            acc[nb] = __builtin_amdgcn_mfma_f32_16x16x32_bf16(a[kb], bf, acc[nb], 0, 0, 0);
        }
    }
    // epilogue: C layout col = lane&15, row = quad*4 + reg
    float dv[4];
    int rbase = row0 + quad * 4;
#pragma unroll
    for (int reg = 0; reg < 4; reg++) dv[reg] = dis[min(rbase + reg, N - 1)];
#pragma unroll
    for (int reg = 0; reg < 4; reg++) {
        int r = rbase + reg;
        if (r < N) {
            u16* gr = gb + (size_t)r * F1 + m;
#pragma unroll
            for (int nb = 0; nb < 8; nb++)
                gr[nb * 16] = (u16)bf16rne(acc[nb][reg] * dv[reg]);
        }
    }
}

// ---------------- Aggregation 1: z(bf16) = relu(dis[i]*(g1[i] + sum g1[src]) + b1) ----------------
// Wave = 1 node. 4 lane-groups of 16; each group gathers one full 256B source row
// (16 lanes x uint4). Chunk = 16 edges -> 4 gathers in flight per lane, exec-masked
// (zero-init + unconditional accumulate of zeros). Next chunk's adj indices are
// prefetched under the current chunk's gather latency.
// Cross-group reduce: shfl_xor 16, 32.

__global__ __launch_bounds__(256) void k_agg1(const uint4* __restrict__ g1,
                                              const int* __restrict__ rowptr,
                                              const int* __restrict__ adj,
                                              const float* __restrict__ dis,
                                              const float* __restrict__ b,
                                              uint4* __restrict__ z, int N) {
    int node = __builtin_amdgcn_readfirstlane(blockIdx.x * 4 + (threadIdx.x >> 6));
    if (node >= N) return;
    int lane = threadIdx.x & 63;
    int grp = lane >> 4;        // 0..3
    int sub = lane & 15;        // col chunk: cols [8*sub, 8*sub+8)
    float ax[8];
#pragma unroll
    for (int i = 0; i < 8; i++) ax[i] = 0.0f;
    int s = rowptr[node], e = rowptr[node + 1];
    if (grp == 0) acc8(ax, g1[(size_t)node * 16 + sub]);   // self-loop term, once
    const uint4 z4 = make_uint4(0u, 0u, 0u, 0u);
    // preload chunk 0 adj (4-deep, masked)
    int i0 = s + grp;
    bool p0 = i0 < e, p1 = i0 + 4 < e, p2 = i0 + 8 < e, p3 = i0 + 12 < e;
    int c0 = 0, c1 = 0, c2 = 0, c3 = 0;
    if (p0) c0 = adj[i0];
    if (p1) c1 = adj[i0 + 4];
    if (p2) c2 = adj[i0 + 8];
    if (p3) c3 = adj[i0 + 12];
    for (int j = s; j < e; j += 16) {
        // issue all 4 gathers for the current chunk
        uint4 v0 = z4, v1 = z4, v2 = z4, v3 = z4;
        if (p0) v0 = g1[(size_t)c0 * 16 + sub];
        if (p1) v1 = g1[(size_t)c1 * 16 + sub];
        if (p2) v2 = g1[(size_t)c2 * 16 + sub];
        if (p3) v3 = g1[(size_t)c3 * 16 + sub];
        // prefetch next chunk's adj under gather latency
        int in0 = j + 16 + grp;
        p0 = in0 < e; p1 = in0 + 4 < e; p2 = in0 + 8 < e; p3 = in0 + 12 < e;
        if (p0) c0 = adj[in0];
        if (p1) c1 = adj[in0 + 4];
        if (p2) c2 = adj[in0 + 8];
        if (p3) c3 = adj[in0 + 12];
        // accumulate (zeros for masked-off sub-chunks are identity)
        acc8(ax, v0);
        acc8(ax, v1);
        acc8(ax, v2);
        acc8(ax, v3);
    }
#pragma unroll
    for (int i = 0; i < 8; i++) {
        ax[i] += __shfl_xor(ax[i], 16);
        ax[i] += __shfl_xor(ax[i], 32);
    }
    if (grp == 0) {
        float d = dis[node];
        float4 b0 = *(const float4*)(b + 8 * sub);
        float4 b1 = *(const float4*)(b + 8 * sub + 4);
        float o[8];
        o[0] = fmaxf(fmaf(d, ax[0], b0.x), 0.0f);
        o[1] = fmaxf(fmaf(d, ax[1], b0.y), 0.0f);
        o[2] = fmaxf(fmaf(d, ax[2], b0.z), 0.0f);
        o[3] = fmaxf(fmaf(d, ax[3], b0.w), 0.0f);
        o[4] = fmaxf(fmaf(d, ax[4], b1.x), 0.0f);
        o[5] = fmaxf(fmaf(d, ax[5], b1.y), 0.0f);
        o[6] = fmaxf(fmaf(d, ax[6], b1.z), 0.0f);
        o[7] = fmaxf(fmaf(d, ax[7], b1.w), 0.0f);
        uint4 ov;
        ov.x = pack2(o[0], o[1]); ov.y = pack2(o[2], o[3]);
        ov.z = pack2(o[4], o[5]); ov.w = pack2(o[6], o[7]);
        z[(size_t)node * 16 + sub] = ov;
    }
}

// ---------------- GEMM 2 (MFMA): g2(bf16) = dis[row] * (z @ W2) ----------------

__global__ __launch_bounds__(256, 4) void k_gemm2(const u32* __restrict__ z,
                                                  const uint4* __restrict__ w2f,
                                                  const float* __restrict__ dis,
                                                  u16* __restrict__ gb, int N) {
    int lane = threadIdx.x & 63;
    int wave = threadIdx.x >> 6;
    int m = lane & 15, quad = lane >> 4;
    int row0 = blockIdx.x * 64 + wave * 16;
    int arow = min(row0 + m, N - 1);
    const u32* zr = z + (size_t)arow * 64 + quad * 4;
    bf16x8 a[4];
#pragma unroll
    for (int kb = 0; kb < 4; kb++) {
        uint4 za = *(const uint4*)(zr + kb * 16);
        a[kb] = *(bf16x8*)&za;
    }
    f32x4 acc[4];
#pragma unroll
    for (int nb = 0; nb < 4; nb++) acc[nb] = (f32x4)(0.0f);
#pragma unroll
    for (int nb = 0; nb < 4; nb++) {
#pragma unroll
        for (int kb = 0; kb < 4; kb++) {
            uint4 braw = w2f[(kb * 4 + nb) * 64 + lane];
            bf16x8 bf = *(bf16x8*)&braw;
            acc[nb] = __builtin_amdgcn_mfma_f32_16x16x32_bf16(a[kb], bf, acc[nb], 0, 0, 0);
        }
    }
    float dv[4];
    int rbase = row0 + quad * 4;
#pragma unroll
    for (int reg = 0; reg < 4; reg++) dv[reg] = dis[min(rbase + reg, N - 1)];
#pragma unroll
    for (int reg = 0; reg < 4; reg++) {
        int r = rbase + reg;
        if (r < N) {
            u16* gr = gb + (size_t)r * F2 + m;
#pragma unroll
            for (int nb = 0; nb < 4; nb++)
                gr[nb * 16] = (u16)bf16rne(acc[nb][reg] * dv[reg]);
        }
    }
}

// ---------------- Aggregation 2: out(fp32) = dis[i]*(g2[i] + sum g2[src]) + b2 ----------------
// Wave = 1 node. 8 lane-groups of 8; each group gathers one 128B source row.
// Chunk = 32 edges -> 4 gathers in flight per lane, exec-masked, adj prefetch.
// Reduce: shfl_xor 8, 16, 32.

__global__ __launch_bounds__(256) void k_agg2(const uint4* __restrict__ g,
                                              const int* __restrict__ rowptr,
                                              const int* __restrict__ adj,
                                              const float* __restrict__ dis,
                                              const float* __restrict__ b,
                                              float* __restrict__ out, int N) {
    int node = __builtin_amdgcn_readfirstlane(blockIdx.x * 4 + (threadIdx.x >> 6));
    if (node >= N) return;
    int lane = threadIdx.x & 63;
    int grp = lane >> 3;        // 0..7
    int sub = lane & 7;         // col chunk: cols [8*sub, 8*sub+8)
    float ax[8];
#pragma unroll
    for (int i = 0; i < 8; i++) ax[i] = 0.0f;
    int s = rowptr[node], e = rowptr[node + 1];
    if (grp == 0) acc8(ax, g[(size_t)node * 8 + sub]);   // self-loop term
    const uint4 z4 = make_uint4(0u, 0u, 0u, 0u);
    // preload chunk 0 adj (4-deep, masked)
    int i0 = s + grp;
    bool p0 = i0 < e, p1 = i0 + 8 < e, p2 = i0 + 16 < e, p3 = i0 + 24 < e;
    int c0 = 0, c1 = 0, c2 = 0, c3 = 0;
    if (p0) c0 = adj[i0];
    if (p1) c1 = adj[i0 + 8];
    if (p2) c2 = adj[i0 + 16];
    if (p3) c3 = adj[i0 + 24];
    for (int j = s; j < e; j += 32) {
        uint4 v0 = z4, v1 = z4, v2 = z4, v3 = z4;
        if (p0) v0 = g[(size_t)c0 * 8 + sub];
        if (p1) v1 = g[(size_t)c1 * 8 + sub];
        if (p2) v2 = g[(size_t)c2 * 8 + sub];
        if (p3) v3 = g[(size_t)c3 * 8 + sub];
        int in0 = j + 32 + grp;
        p0 = in0 < e; p1 = in0 + 8 < e; p2 = in0 + 16 < e; p3 = in0 + 24 < e;
        if (p0) c0 = adj[in0];
        if (p1) c1 = adj[in0 + 8];
        if (p2) c2 = adj[in0 + 16];
        if (p3) c3 = adj[in0 + 24];
        acc8(ax, v0);
        acc8(ax, v1);
        acc8(ax, v2);
        acc8(ax, v3);
    }
#pragma unroll
    for (int i = 0; i < 8; i++) {
        ax[i] += __shfl_xor(ax[i], 8);
        ax[i] += __shfl_xor(ax[i], 16);
        ax[i] += __shfl_xor(ax[i], 32);
    }
    if (grp == 0) {
        float d = dis[node];
        float4 b0 = *(const float4*)(b + 8 * sub);
        float4 b1 = *(const float4*)(b + 8 * sub + 4);
        float4 o0, o1;
        o0.x = fmaf(d, ax[0], b0.x); o0.y = fmaf(d, ax[1], b0.y);
        o0.z = fmaf(d, ax[2], b0.z); o0.w = fmaf(d, ax[3], b0.w);
        o1.x = fmaf(d, ax[4], b1.x); o1.y = fmaf(d, ax[5], b1.y);
        o1.z = fmaf(d, ax[6], b1.z); o1.w = fmaf(d, ax[7], b1.w);
        float4* op = (float4*)(out + (size_t)node * F2 + 8 * sub);
        op[0] = o0;
        op[1] = o1;
    }
}

// ---------------- launch ----------------

extern "C" void kernel_launch(void* const* d_in, const int* in_sizes, int n_in,
                              void* d_out, int out_size, void* d_ws, size_t ws_size,
                              hipStream_t stream) {
    const float* x  = (const float*)d_in[0];
    const int*   ei = (const int*)d_in[1];
    const float* W1 = (const float*)d_in[2];
    const float* b1 = (const float*)d_in[3];
    const float* W2 = (const float*)d_in[4];
    const float* b2 = (const float*)d_in[5];
    float* out = (float*)d_out;

    const int N = in_sizes[0] / F1;
    const int E = in_sizes[1] / 2;
    const int NB = (N + BSZ - 1) >> BSH;   // 196 for N=100000; must be <= 256
    const int* rowv = ei;        // sources
    const int* colv = ei + E;    // targets

    char* ws = (char*)d_ws;
    size_t off = 0;
    auto take = [&](size_t bytes) -> void* {
        void* p = ws + off;
        off += (bytes + 255) & ~(size_t)255;
        return p;
    };
    u16*   g1b     = (u16*)take((size_t)N * F1 * 2);   // 25.6 MB (bf16)
    u32*   zb      = (u32*)take((size_t)N * 64 * 4);   // 25.6 MB (bf16 packed)
    u16*   g2b     = g1b;                // g1 dead after agg1 -> reuse
    u32*   ebuf    = (u32*)g1b;          // ebuf (6.4 MB) dead before gemm1 writes g1
    float* dis     = (float*)take((size_t)N * 4);
    int*   rowptr  = (int*)take((size_t)(N + 1) * 4);
    int*   adj     = (int*)take((size_t)E * 4);        // 6.4 MB
    uint4* w1f     = (uint4*)take(4 * 8 * 64 * 16);    // 32 KB bf16 frag-order W1
    uint4* w2f     = (uint4*)take(4 * 4 * 64 * 16);    // 16 KB bf16 frag-order W2
    int*   bucket_cnt  = (int*)take(256 * 4);
    int*   bucket_base = (int*)take(257 * 4);
    int*   bucket_cur  = (int*)take(256 * 4);

    hipMemsetAsync(bucket_cnt, 0, 256 * 4, stream);

    k_wprep<<<12, 256, 0, stream>>>(W1, W2, w1f, w2f);

    k_bhist<<<256, 256, 0, stream>>>(colv, bucket_cnt, E);
    k_bscan<<<1, 256, 0, stream>>>(bucket_cnt, bucket_base, bucket_cur, rowptr + N, NB, E);
    k_part<<<(E + 4095) / 4096, 256, 0, stream>>>(rowv, colv, bucket_cur, ebuf, E);
    k_bfill<<<NB, BSZ, 0, stream>>>(ebuf, bucket_base, rowptr, dis, adj, N);

    int gblocks = (N + 63) / 64;
    k_gemm1<<<gblocks, 256, 0, stream>>>(x, w1f, dis, g1b, N);
    k_agg1<<<(N + 3) / 4, 256, 0, stream>>>((const uint4*)g1b, rowptr, adj, dis, b1,
                                            (uint4*)zb, N);
    k_gemm2<<<gblocks, 256, 0, stream>>>(zb, w2f, dis, g2b, N);
    k_agg2<<<(N + 3) / 4, 256, 0, stream>>>((const uint4*)g2b, rowptr, adj, dis, b2, out, N);
}

// Round 2
// 274.423 us; speedup vs baseline: 1.0399x; 1.0222x over previous
//
#include <hip/hip_runtime.h>

#define F1 128
#define F2 64
// bucket = 512 consecutive nodes; requires N <= 256*512 and N < 2^17 (u32 ebuf pack)
#define BSH 9
#define BSZ 512
// LDS staging capacity for one bucket's edge list in k_bfill (48 KB).
// Expected bucket size ~8200 (sigma ~90); fallback path covers overflow.
#define BFILL_CAP 12288

typedef unsigned int u32;
typedef unsigned short u16;
typedef __attribute__((ext_vector_type(8))) short bf16x8;   // 8 bf16 (4 VGPRs)
typedef __attribute__((ext_vector_type(4))) float f32x4;

// bf16 helpers (manual, header-version-proof). RNE pack, shift unpack.
__device__ __forceinline__ u32 bf16rne(float f) {
    u32 u = __float_as_uint(f);
    return (u + 0x7FFFu + ((u >> 16) & 1u)) >> 16;
}
__device__ __forceinline__ u32 pack2(float lo, float hi) {
    return bf16rne(lo) | (bf16rne(hi) << 16);
}
__device__ __forceinline__ float bflo(u32 u) { return __uint_as_float(u << 16); }
__device__ __forceinline__ float bfhi(u32 u) { return __uint_as_float(u & 0xFFFF0000u); }

__device__ __forceinline__ void acc8(float* ax, uint4 v) {
    ax[0] += bflo(v.x); ax[1] += bfhi(v.x);
    ax[2] += bflo(v.y); ax[3] += bfhi(v.y);
    ax[4] += bflo(v.z); ax[5] += bfhi(v.z);
    ax[6] += bflo(v.w); ax[7] += bfhi(v.w);
}

// ---------------- CSR build (bucketed, LDS atomics) ----------------

__global__ __launch_bounds__(256) void k_bhist(const int* __restrict__ colv,
                                               int* __restrict__ bucket_cnt, int E) {
    __shared__ int l[256];
    int t = threadIdx.x;
    l[t] = 0;
    __syncthreads();
    for (int e = blockIdx.x * blockDim.x + t; e < E; e += gridDim.x * blockDim.x)
        atomicAdd(&l[colv[e] >> BSH], 1);
    __syncthreads();
    if (l[t]) atomicAdd(&bucket_cnt[t], l[t]);
}

__global__ __launch_bounds__(256) void k_bscan(const int* __restrict__ bucket_cnt,
                                               int* __restrict__ bucket_base,
                                               int* __restrict__ bucket_cur,
                                               int* __restrict__ rowptr_last,
                                               int NB, int E) {
    __shared__ int s[256];
    int t = threadIdx.x;
    int v = (t < NB) ? bucket_cnt[t] : 0;
    s[t] = v;
    __syncthreads();
    for (int d = 1; d < 256; d <<= 1) {
        int u = (t >= d) ? s[t - d] : 0;
        __syncthreads();
        s[t] += u;
        __syncthreads();
    }
    int excl = s[t] - v;
    if (t < NB) { bucket_base[t] = excl; bucket_cur[t] = excl; }
    if (t == NB - 1) bucket_base[NB] = s[t];
    if (t == 0) *rowptr_last = E;
}

// Stage 4096 edges, block-local counting sort by bucket into LDS, reserve
// per-bucket runs with ONE global atomic per bucket, then write runs out
// coalesced (bucket-sorted order -> consecutive global addresses per run).
__global__ __launch_bounds__(256) void k_part(const int* __restrict__ rowv,
                                              const int* __restrict__ colv,
                                              int* __restrict__ bucket_cur,
                                              u32* __restrict__ ebuf, int E) {
    __shared__ int lcnt[256], lexcl[256], lcur[256], lbase[256];
    __shared__ int stot;
    __shared__ u32 sval[4096];
    __shared__ u16 sbkt[4096];
    int t = threadIdx.x;
    lcnt[t] = 0;
    __syncthreads();
    int rows[16], cols[16];
    int e0 = blockIdx.x * 4096;
#pragma unroll
    for (int it = 0; it < 16; it++) {
        int e = e0 + it * 256 + t;
        bool v = e < E;
        cols[it] = v ? colv[e] : -1;
        rows[it] = v ? rowv[e] : 0;
        if (v) atomicAdd(&lcnt[cols[it] >> BSH], 1);
    }
    __syncthreads();
    // block-local inclusive scan of lcnt -> lexcl (exclusive)
    int v = lcnt[t];
    int s = v;
    lexcl[t] = s;   // temporarily inclusive in lexcl via ping-pong on lexcl
    __syncthreads();
    for (int d = 1; d < 256; d <<= 1) {
        int u = (t >= d) ? lexcl[t - d] : 0;
        __syncthreads();
        lexcl[t] += u;
        __syncthreads();
    }
    int incl = lexcl[t];
    __syncthreads();
    lexcl[t] = incl - v;      // now exclusive
    lcur[t] = incl - v;
    if (v) lbase[t] = atomicAdd(&bucket_cur[t], v);
    if (t == 255) stot = incl;
    __syncthreads();
    // place edges bucket-sorted into LDS
#pragma unroll
    for (int it = 0; it < 16; it++) {
        if (cols[it] >= 0) {
            int b = cols[it] >> BSH;
            int pos = atomicAdd(&lcur[b], 1);
            sval[pos] = ((u32)(cols[it] & (BSZ - 1)) << 17) | (u32)rows[it];
            sbkt[pos] = (u16)b;
        }
    }
    __syncthreads();
    // coalesced write-out: consecutive i within a bucket run -> consecutive addrs
    int total = stot;
    for (int i = t; i < total; i += 256) {
        int b = sbkt[i];
        ebuf[lbase[b] + (i - lexcl[b])] = sval[i];
    }
}

// One block per bucket: per-node counts + scan + placement via LDS, then
// identity-mapped coalesced copy LDS -> adj (sorted local order IS the
// final global order within the bucket).
__global__ __launch_bounds__(512) void k_bfill(const u32* __restrict__ ebuf,
                                               const int* __restrict__ bucket_base,
                                               int* __restrict__ rowptr,
                                               float* __restrict__ dis,
                                               int* __restrict__ adj, int N) {
    __shared__ int cnt[BSZ], scn[BSZ], cur[BSZ];
    __shared__ int sadj[BFILL_CAP];
    int t = threadIdx.x;
    int b = blockIdx.x;
    int e0 = bucket_base[b], e1 = bucket_base[b + 1];
    int len = e1 - e0;
    cnt[t] = 0;
    __syncthreads();
    for (int i = e0 + t; i < e1; i += BSZ)
        atomicAdd(&cnt[ebuf[i] >> 17], 1);
    __syncthreads();
    scn[t] = cnt[t];
    __syncthreads();
    for (int d = 1; d < BSZ; d <<= 1) {
        int u = (t >= d) ? scn[t - d] : 0;
        __syncthreads();
        scn[t] += u;
        __syncthreads();
    }
    int excl = scn[t] - cnt[t];
    cur[t] = excl;
    int node = (b << BSH) + t;
    if (node < N) {
        rowptr[node] = e0 + excl;
        dis[node] = rsqrtf((float)(cnt[t] + 1));   // +1 self loop
    }
    __syncthreads();
    if (len <= BFILL_CAP) {
        // LDS-staged: scatter into LDS, then coalesced copy out
        for (int i = e0 + t; i < e1; i += BSZ) {
            u32 p = ebuf[i];
            int c = p >> 17;
            int r = (int)(p & 0x1FFFFu);
            int pos = atomicAdd(&cur[c], 1);
            sadj[pos] = r;
        }
        __syncthreads();
        for (int i = t; i < len; i += BSZ)
            adj[e0 + i] = sadj[i];
    } else {
        // fallback: direct scatter (correctness safety for oversized buckets)
        for (int i = e0 + t; i < e1; i += BSZ) {
            u32 p = ebuf[i];
            int c = p >> 17;
            int r = (int)(p & 0x1FFFFu);
            int pos = atomicAdd(&cur[c], 1);
            adj[e0 + pos] = r;
        }
    }
}

// ---------------- W prep: fp32 W[K][C] -> bf16 B-frag order [kb][nb][lane][j] ----------------
// Frag layout for mfma_f32_16x16x32_bf16 B-operand: n = lane&15, k = (lane>>4)*8 + j.
// Blocks 0-7: W1 (NBc=8). Blocks 8-11: W2 (NBc=4).

__device__ __forceinline__ void wprep_do(const float* __restrict__ W,
                                         uint4* __restrict__ wf, int NBc, int t) {
    int lane = t & 63;
    int rem = t >> 6;
    int nb = rem % NBc;
    int kb = rem / NBc;
    int C = NBc * 16;
    int col = nb * 16 + (lane & 15);
    int krow = kb * 32 + (lane >> 4) * 8;
    u32 w[4];
#pragma unroll
    for (int p = 0; p < 4; p++) {
        float lo = W[(size_t)(krow + 2 * p) * C + col];
        float hi = W[(size_t)(krow + 2 * p + 1) * C + col];
        w[p] = pack2(lo, hi);
    }
    wf[t] = make_uint4(w[0], w[1], w[2], w[3]);
}

__global__ __launch_bounds__(256) void k_wprep(const float* __restrict__ W1,
                                               const float* __restrict__ W2,
                                               uint4* __restrict__ w1f,
                                               uint4* __restrict__ w2f) {
    int blk = blockIdx.x;
    if (blk < 8) wprep_do(W1, w1f, 8, blk * 256 + threadIdx.x);
    else         wprep_do(W2, w2f, 4, (blk - 8) * 256 + threadIdx.x);
}

// ---------------- GEMM 1 (MFMA): g1(bf16) = dis[row] * (x @ W1) ----------------

__global__ __launch_bounds__(256, 4) void k_gemm1(const float* __restrict__ x,
                                                  const uint4* __restrict__ w1f,
                                                  const float* __restrict__ dis,
                                                  u16* __restrict__ gb, int N) {
    int lane = threadIdx.x & 63;
    int wave = threadIdx.x >> 6;
    int m = lane & 15, quad = lane >> 4;
    int row0 = blockIdx.x * 64 + wave * 16;
    int arow = min(row0 + m, N - 1);
    const float* xr = x + (size_t)arow * F1 + quad * 8;
    bf16x8 a[4];
#pragma unroll
    for (int kb = 0; kb < 4; kb++) {
        float4 lo = *(const float4*)(xr + kb * 32);
        float4 hi = *(const float4*)(xr + kb * 32 + 4);
        a[kb][0] = (short)bf16rne(lo.x); a[kb][1] = (short)bf16rne(lo.y);
        a[kb][2] = (short)bf16rne(lo.z); a[kb][3] = (short)bf16rne(lo.w);
        a[kb][4] = (short)bf16rne(hi.x); a[kb][5] = (short)bf16rne(hi.y);
        a[kb][6] = (short)bf16rne(hi.z); a[kb][7] = (short)bf16rne(hi.w);
    }
    f32x4 acc[8];
#pragma unroll
    for (int nb = 0; nb < 8; nb++) acc[nb] = (f32x4)(0.0f);
#pragma unroll
    for (int nb = 0; nb < 8; nb++) {
#pragma unroll
        for (int kb = 0; kb < 4; kb++) {
            uint4 braw = w1f[(kb * 8 + nb) * 64 + lane];
            bf16x8 bf = *(bf16x8*)&braw;
            acc[nb] = __builtin_amdgcn_mfma_f32_16x16x32_bf16(a[kb], bf, acc[nb], 0, 0, 0);
        }
    }
    // epilogue: C layout col = lane&15, row = quad*4 + reg
    float dv[4];
    int rbase = row0 + quad * 4;
#pragma unroll
    for (int reg = 0; reg < 4; reg++) dv[reg] = dis[min(rbase + reg, N - 1)];
#pragma unroll
    for (int reg = 0; reg < 4; reg++) {
        int r = rbase + reg;
        if (r < N) {
            u16* gr = gb + (size_t)r * F1 + m;
#pragma unroll
            for (int nb = 0; nb < 8; nb++)
                gr[nb * 16] = (u16)bf16rne(acc[nb][reg] * dv[reg]);
        }
    }
}

// ---------------- Aggregation 1: z(bf16) = relu(dis[i]*(g1[i] + sum g1[src]) + b1) ----------------
// Wave = 1 node. 4 lane-groups of 16; chunk = 16 edges, 4 gathers in flight per
// lane, exec-masked, next chunk's adj prefetched. Cross-group reduce: shfl_xor.

__global__ __launch_bounds__(256) void k_agg1(const uint4* __restrict__ g1,
                                              const int* __restrict__ rowptr,
                                              const int* __restrict__ adj,
                                              const float* __restrict__ dis,
                                              const float* __restrict__ b,
                                              uint4* __restrict__ z, int N) {
    int node = __builtin_amdgcn_readfirstlane(blockIdx.x * 4 + (threadIdx.x >> 6));
    if (node >= N) return;
    int lane = threadIdx.x & 63;
    int grp = lane >> 4;        // 0..3
    int sub = lane & 15;        // col chunk: cols [8*sub, 8*sub+8)
    float ax[8];
#pragma unroll
    for (int i = 0; i < 8; i++) ax[i] = 0.0f;
    int s = rowptr[node], e = rowptr[node + 1];
    if (grp == 0) acc8(ax, g1[(size_t)node * 16 + sub]);   // self-loop term, once
    const uint4 z4 = make_uint4(0u, 0u, 0u, 0u);
    int i0 = s + grp;
    bool p0 = i0 < e, p1 = i0 + 4 < e, p2 = i0 + 8 < e, p3 = i0 + 12 < e;
    int c0 = 0, c1 = 0, c2 = 0, c3 = 0;
    if (p0) c0 = adj[i0];
    if (p1) c1 = adj[i0 + 4];
    if (p2) c2 = adj[i0 + 8];
    if (p3) c3 = adj[i0 + 12];
    for (int j = s; j < e; j += 16) {
        uint4 v0 = z4, v1 = z4, v2 = z4, v3 = z4;
        if (p0) v0 = g1[(size_t)c0 * 16 + sub];
        if (p1) v1 = g1[(size_t)c1 * 16 + sub];
        if (p2) v2 = g1[(size_t)c2 * 16 + sub];
        if (p3) v3 = g1[(size_t)c3 * 16 + sub];
        int in0 = j + 16 + grp;
        p0 = in0 < e; p1 = in0 + 4 < e; p2 = in0 + 8 < e; p3 = in0 + 12 < e;
        if (p0) c0 = adj[in0];
        if (p1) c1 = adj[in0 + 4];
        if (p2) c2 = adj[in0 + 8];
        if (p3) c3 = adj[in0 + 12];
        acc8(ax, v0);
        acc8(ax, v1);
        acc8(ax, v2);
        acc8(ax, v3);
    }
#pragma unroll
    for (int i = 0; i < 8; i++) {
        ax[i] += __shfl_xor(ax[i], 16);
        ax[i] += __shfl_xor(ax[i], 32);
    }
    if (grp == 0) {
        float d = dis[node];
        float4 b0 = *(const float4*)(b + 8 * sub);
        float4 b1 = *(const float4*)(b + 8 * sub + 4);
        float o[8];
        o[0] = fmaxf(fmaf(d, ax[0], b0.x), 0.0f);
        o[1] = fmaxf(fmaf(d, ax[1], b0.y), 0.0f);
        o[2] = fmaxf(fmaf(d, ax[2], b0.z), 0.0f);
        o[3] = fmaxf(fmaf(d, ax[3], b0.w), 0.0f);
        o[4] = fmaxf(fmaf(d, ax[4], b1.x), 0.0f);
        o[5] = fmaxf(fmaf(d, ax[5], b1.y), 0.0f);
        o[6] = fmaxf(fmaf(d, ax[6], b1.z), 0.0f);
        o[7] = fmaxf(fmaf(d, ax[7], b1.w), 0.0f);
        uint4 ov;
        ov.x = pack2(o[0], o[1]); ov.y = pack2(o[2], o[3]);
        ov.z = pack2(o[4], o[5]); ov.w = pack2(o[6], o[7]);
        z[(size_t)node * 16 + sub] = ov;
    }
}

// ---------------- GEMM 2 (MFMA): g2(bf16) = dis[row] * (z @ W2) ----------------

__global__ __launch_bounds__(256, 4) void k_gemm2(const u32* __restrict__ z,
                                                  const uint4* __restrict__ w2f,
                                                  const float* __restrict__ dis,
                                                  u16* __restrict__ gb, int N) {
    int lane = threadIdx.x & 63;
    int wave = threadIdx.x >> 6;
    int m = lane & 15, quad = lane >> 4;
    int row0 = blockIdx.x * 64 + wave * 16;
    int arow = min(row0 + m, N - 1);
    const u32* zr = z + (size_t)arow * 64 + quad * 4;
    bf16x8 a[4];
#pragma unroll
    for (int kb = 0; kb < 4; kb++) {
        uint4 za = *(const uint4*)(zr + kb * 16);
        a[kb] = *(bf16x8*)&za;
    }
    f32x4 acc[4];
#pragma unroll
    for (int nb = 0; nb < 4; nb++) acc[nb] = (f32x4)(0.0f);
#pragma unroll
    for (int nb = 0; nb < 4; nb++) {
#pragma unroll
        for (int kb = 0; kb < 4; kb++) {
            uint4 braw = w2f[(kb * 4 + nb) * 64 + lane];
            bf16x8 bf = *(bf16x8*)&braw;
            acc[nb] = __builtin_amdgcn_mfma_f32_16x16x32_bf16(a[kb], bf, acc[nb], 0, 0, 0);
        }
    }
    float dv[4];
    int rbase = row0 + quad * 4;
#pragma unroll
    for (int reg = 0; reg < 4; reg++) dv[reg] = dis[min(rbase + reg, N - 1)];
#pragma unroll
    for (int reg = 0; reg < 4; reg++) {
        int r = rbase + reg;
        if (r < N) {
            u16* gr = gb + (size_t)r * F2 + m;
#pragma unroll
            for (int nb = 0; nb < 4; nb++)
                gr[nb * 16] = (u16)bf16rne(acc[nb][reg] * dv[reg]);
        }
    }
}

// ---------------- Aggregation 2: out(fp32) = dis[i]*(g2[i] + sum g2[src]) + b2 ----------------
// Wave = 1 node. 8 lane-groups of 8; chunk = 32 edges, 4 gathers in flight,
// exec-masked, adj prefetch. Reduce: shfl_xor 8, 16, 32.

__global__ __launch_bounds__(256) void k_agg2(const uint4* __restrict__ g,
                                              const int* __restrict__ rowptr,
                                              const int* __restrict__ adj,
                                              const float* __restrict__ dis,
                                              const float* __restrict__ b,
                                              float* __restrict__ out, int N) {
    int node = __builtin_amdgcn_readfirstlane(blockIdx.x * 4 + (threadIdx.x >> 6));
    if (node >= N) return;
    int lane = threadIdx.x & 63;
    int grp = lane >> 3;        // 0..7
    int sub = lane & 7;         // col chunk: cols [8*sub, 8*sub+8)
    float ax[8];
#pragma unroll
    for (int i = 0; i < 8; i++) ax[i] = 0.0f;
    int s = rowptr[node], e = rowptr[node + 1];
    if (grp == 0) acc8(ax, g[(size_t)node * 8 + sub]);   // self-loop term
    const uint4 z4 = make_uint4(0u, 0u, 0u, 0u);
    int i0 = s + grp;
    bool p0 = i0 < e, p1 = i0 + 8 < e, p2 = i0 + 16 < e, p3 = i0 + 24 < e;
    int c0 = 0, c1 = 0, c2 = 0, c3 = 0;
    if (p0) c0 = adj[i0];
    if (p1) c1 = adj[i0 + 8];
    if (p2) c2 = adj[i0 + 16];
    if (p3) c3 = adj[i0 + 24];
    for (int j = s; j < e; j += 32) {
        uint4 v0 = z4, v1 = z4, v2 = z4, v3 = z4;
        if (p0) v0 = g[(size_t)c0 * 8 + sub];
        if (p1) v1 = g[(size_t)c1 * 8 + sub];
        if (p2) v2 = g[(size_t)c2 * 8 + sub];
        if (p3) v3 = g[(size_t)c3 * 8 + sub];
        int in0 = j + 32 + grp;
        p0 = in0 < e; p1 = in0 + 8 < e; p2 = in0 + 16 < e; p3 = in0 + 24 < e;
        if (p0) c0 = adj[in0];
        if (p1) c1 = adj[in0 + 8];
        if (p2) c2 = adj[in0 + 16];
        if (p3) c3 = adj[in0 + 24];
        acc8(ax, v0);
        acc8(ax, v1);
        acc8(ax, v2);
        acc8(ax, v3);
    }
#pragma unroll
    for (int i = 0; i < 8; i++) {
        ax[i] += __shfl_xor(ax[i], 8);
        ax[i] += __shfl_xor(ax[i], 16);
        ax[i] += __shfl_xor(ax[i], 32);
    }
    if (grp == 0) {
        float d = dis[node];
        float4 b0 = *(const float4*)(b + 8 * sub);
        float4 b1 = *(const float4*)(b + 8 * sub + 4);
        float4 o0, o1;
        o0.x = fmaf(d, ax[0], b0.x); o0.y = fmaf(d, ax[1], b0.y);
        o0.z = fmaf(d, ax[2], b0.z); o0.w = fmaf(d, ax[3], b0.w);
        o1.x = fmaf(d, ax[4], b1.x); o1.y = fmaf(d, ax[5], b1.y);
        o1.z = fmaf(d, ax[6], b1.z); o1.w = fmaf(d, ax[7], b1.w);
        float4* op = (float4*)(out + (size_t)node * F2 + 8 * sub);
        op[0] = o0;
        op[1] = o1;
    }
}

// ---------------- launch ----------------

extern "C" void kernel_launch(void* const* d_in, const int* in_sizes, int n_in,
                              void* d_out, int out_size, void* d_ws, size_t ws_size,
                              hipStream_t stream) {
    const float* x  = (const float*)d_in[0];
    const int*   ei = (const int*)d_in[1];
    const float* W1 = (const float*)d_in[2];
    const float* b1 = (const float*)d_in[3];
    const float* W2 = (const float*)d_in[4];
    const float* b2 = (const float*)d_in[5];
    float* out = (float*)d_out;

    const int N = in_sizes[0] / F1;
    const int E = in_sizes[1] / 2;
    const int NB = (N + BSZ - 1) >> BSH;   // 196 for N=100000; must be <= 256
    const int* rowv = ei;        // sources
    const int* colv = ei + E;    // targets

    char* ws = (char*)d_ws;
    size_t off = 0;
    auto take = [&](size_t bytes) -> void* {
        void* p = ws + off;
        off += (bytes + 255) & ~(size_t)255;
        return p;
    };
    u16*   g1b     = (u16*)take((size_t)N * F1 * 2);   // 25.6 MB (bf16)
    u32*   zb      = (u32*)take((size_t)N * 64 * 4);   // 25.6 MB (bf16 packed)
    u16*   g2b     = g1b;                // g1 dead after agg1 -> reuse
    u32*   ebuf    = (u32*)g1b;          // ebuf (6.4 MB) dead before gemm1 writes g1
    float* dis     = (float*)take((size_t)N * 4);
    int*   rowptr  = (int*)take((size_t)(N + 1) * 4);
    int*   adj     = (int*)take((size_t)E * 4);        // 6.4 MB
    uint4* w1f     = (uint4*)take(4 * 8 * 64 * 16);    // 32 KB bf16 frag-order W1
    uint4* w2f     = (uint4*)take(4 * 4 * 64 * 16);    // 16 KB bf16 frag-order W2
    int*   bucket_cnt  = (int*)take(256 * 4);
    int*   bucket_base = (int*)take(257 * 4);
    int*   bucket_cur  = (int*)take(256 * 4);

    hipMemsetAsync(bucket_cnt, 0, 256 * 4, stream);

    k_wprep<<<12, 256, 0, stream>>>(W1, W2, w1f, w2f);

    k_bhist<<<256, 256, 0, stream>>>(colv, bucket_cnt, E);
    k_bscan<<<1, 256, 0, stream>>>(bucket_cnt, bucket_base, bucket_cur, rowptr + N, NB, E);
    k_part<<<(E + 4095) / 4096, 256, 0, stream>>>(rowv, colv, bucket_cur, ebuf, E);
    k_bfill<<<NB, BSZ, 0, stream>>>(ebuf, bucket_base, rowptr, dis, adj, N);

    int gblocks = (N + 63) / 64;
    k_gemm1<<<gblocks, 256, 0, stream>>>(x, w1f, dis, g1b, N);
    k_agg1<<<(N + 3) / 4, 256, 0, stream>>>((const uint4*)g1b, rowptr, adj, dis, b1,
                                            (uint4*)zb, N);
    k_gemm2<<<gblocks, 256, 0, stream>>>(zb, w2f, dis, g2b, N);
    k_agg2<<<(N + 3) / 4, 256, 0, stream>>>((const uint4*)g2b, rowptr, adj, dis, b2, out, N);
}